// Round 1
// baseline (999.111 us; speedup 1.0000x reference)
//
#include <hip/hip_runtime.h>
#include <math.h>

#define DM   768
#define DI   1536
#define NDS  16
#define DTR  48
#define XDC  80
#define NB   2
#define SEQL 512
#define NT   (NB*SEQL)
#define BETA 0.9f
#define NSA  3.4445f
#define NSB  (-4.775f)
#define NSC  2.0315f

__device__ __forceinline__ float silu_(float x){ return x / (1.f + __expf(-x)); }

// ---------------- rmsnorm: one block per token ----------------
__global__ void rms_k(const float* __restrict__ X, const float* __restrict__ W,
                      float* __restrict__ O)
{
  const int g = blockIdx.x, tid = threadIdx.x;
  const float* xr = X + (size_t)g*DM;
  float x0 = xr[tid], x1 = xr[tid+256], x2 = xr[tid+512];
  float ss = x0*x0 + x1*x1 + x2*x2;
  #pragma unroll
  for (int m=1; m<=32; m<<=1) ss += __shfl_xor(ss, m);
  __shared__ float ws[4];
  if ((tid & 63) == 0) ws[tid>>6] = ss;
  __syncthreads();
  float sc = rsqrtf((ws[0]+ws[1]+ws[2]+ws[3])*(1.f/DM) + 1e-5f);
  float* o = O + (size_t)g*DM;
  o[tid]     = x0*sc*W[tid];
  o[tid+256] = x1*sc*W[tid+256];
  o[tid+512] = x2*sc*W[tid+512];
}

// ---------------- GEMM: C[r,c] = sum_k A[r*lda+k]*B[c*ldb+k] ----------------
// EPI: 0 none, 1 softplus(x+bias[col]), 2 x+res[r*N+c].  K split over blockIdx.z.
template<int EPI>
__global__ void gemm128(const float* __restrict__ A, int lda,
                        const float* __restrict__ Bw, int ldb,
                        float* __restrict__ Out, float* __restrict__ Part,
                        const float* __restrict__ aux,
                        int M, int N, int K, int SK)
{
  __shared__ float As[16][128], Bs[16][128];
  const int tid = threadIdx.x;
  const int bm = blockIdx.y*128, bn = blockIdx.x*128;
  const int kc = K/SK, kBeg = blockIdx.z*kc, kEnd = kBeg + kc;
  const int lr = tid>>1, lk = (tid&1)<<3;
  const int tx = tid&15, ty = tid>>4;
  float acc[8][8];
  #pragma unroll
  for (int i=0;i<8;i++)
    #pragma unroll
    for (int j=0;j<8;j++) acc[i][j] = 0.f;
  const float* Ap = A + (size_t)(bm+lr)*lda + lk;
  const bool bok = (bn+lr) < N;
  const float* Bp = Bw + (size_t)(bn+lr)*ldb + lk;
  for (int k0=kBeg; k0<kEnd; k0+=16){
    float4 a0 = *(const float4*)(Ap + k0);
    float4 a1 = *(const float4*)(Ap + k0 + 4);
    float4 b0 = {0,0,0,0}, b1 = {0,0,0,0};
    if (bok){ b0 = *(const float4*)(Bp + k0); b1 = *(const float4*)(Bp + k0 + 4); }
    __syncthreads();
    As[lk+0][lr]=a0.x; As[lk+1][lr]=a0.y; As[lk+2][lr]=a0.z; As[lk+3][lr]=a0.w;
    As[lk+4][lr]=a1.x; As[lk+5][lr]=a1.y; As[lk+6][lr]=a1.z; As[lk+7][lr]=a1.w;
    Bs[lk+0][lr]=b0.x; Bs[lk+1][lr]=b0.y; Bs[lk+2][lr]=b0.z; Bs[lk+3][lr]=b0.w;
    Bs[lk+4][lr]=b1.x; Bs[lk+5][lr]=b1.y; Bs[lk+6][lr]=b1.z; Bs[lk+7][lr]=b1.w;
    __syncthreads();
    #pragma unroll
    for (int kk=0;kk<16;kk++){
      float a[8], b[8];
      *(float4*)&a[0] = *(const float4*)&As[kk][ty*4];
      *(float4*)&a[4] = *(const float4*)&As[kk][64+ty*4];
      *(float4*)&b[0] = *(const float4*)&Bs[kk][tx*4];
      *(float4*)&b[4] = *(const float4*)&Bs[kk][64+tx*4];
      #pragma unroll
      for (int i=0;i<8;i++)
        #pragma unroll
        for (int j=0;j<8;j++) acc[i][j] = fmaf(a[i], b[j], acc[i][j]);
    }
  }
  #pragma unroll
  for (int i=0;i<8;i++){
    const int row = bm + ((i<4) ? ty*4+i : 64+ty*4+i-4);
    #pragma unroll
    for (int j=0;j<8;j++){
      const int col = bn + ((j<4) ? tx*4+j : 64+tx*4+j-4);
      if (col < N){
        if (SK == 1){
          float vv = acc[i][j];
          if (EPI==1){ vv += aux[col]; vv = fmaxf(vv,0.f) + log1pf(__expf(-fabsf(vv))); }
          if (EPI==2){ vv += aux[(size_t)row*N+col]; }
          Out[(size_t)row*N+col] = vv;
        } else {
          Part[(size_t)blockIdx.z*M*N + (size_t)row*N+col] = acc[i][j];
        }
      }
    }
  }
}

template<int EPI>
__global__ void gemm64(const float* __restrict__ A, int lda,
                       const float* __restrict__ Bw, int ldb,
                       float* __restrict__ Out, float* __restrict__ Part,
                       const float* __restrict__ aux,
                       int M, int N, int K, int SK)
{
  __shared__ float As[16][64], Bs[16][64];
  const int tid = threadIdx.x;
  const int bm = blockIdx.y*64, bn = blockIdx.x*64;
  const int kc = K/SK, kBeg = blockIdx.z*kc, kEnd = kBeg + kc;
  const int lr = tid>>2, lk = (tid&3)<<2;
  const int tx = tid&15, ty = tid>>4;
  float acc[4][4];
  #pragma unroll
  for (int i=0;i<4;i++)
    #pragma unroll
    for (int j=0;j<4;j++) acc[i][j] = 0.f;
  const float* Ap = A + (size_t)(bm+lr)*lda + lk;
  const bool bok = (bn+lr) < N;
  const float* Bp = Bw + (size_t)(bn+lr)*ldb + lk;
  for (int k0=kBeg; k0<kEnd; k0+=16){
    float4 a0 = *(const float4*)(Ap + k0);
    float4 b0 = {0,0,0,0};
    if (bok) b0 = *(const float4*)(Bp + k0);
    __syncthreads();
    As[lk+0][lr]=a0.x; As[lk+1][lr]=a0.y; As[lk+2][lr]=a0.z; As[lk+3][lr]=a0.w;
    Bs[lk+0][lr]=b0.x; Bs[lk+1][lr]=b0.y; Bs[lk+2][lr]=b0.z; Bs[lk+3][lr]=b0.w;
    __syncthreads();
    #pragma unroll
    for (int kk=0;kk<16;kk++){
      float a[4], b[4];
      *(float4*)a = *(const float4*)&As[kk][ty*4];
      *(float4*)b = *(const float4*)&Bs[kk][tx*4];
      #pragma unroll
      for (int i=0;i<4;i++)
        #pragma unroll
        for (int j=0;j<4;j++) acc[i][j] = fmaf(a[i], b[j], acc[i][j]);
    }
  }
  #pragma unroll
  for (int i=0;i<4;i++){
    const int row = bm + ty*4 + i;
    #pragma unroll
    for (int j=0;j<4;j++){
      const int col = bn + tx*4 + j;
      if (col < N){
        if (SK == 1){
          float vv = acc[i][j];
          if (EPI==1){ vv += aux[col]; vv = fmaxf(vv,0.f) + log1pf(__expf(-fabsf(vv))); }
          if (EPI==2){ vv += aux[(size_t)row*N+col]; }
          Out[(size_t)row*N+col] = vv;
        } else {
          Part[(size_t)blockIdx.z*M*N + (size_t)row*N+col] = acc[i][j];
        }
      }
    }
  }
}

template<int EPI>
__global__ void reduce_k(const float* __restrict__ Part, float* __restrict__ Out,
                         const float* __restrict__ aux, int MN, int SK)
{
  const int i = blockIdx.x*256 + threadIdx.x;
  if (i >= MN) return;
  float s = 0.f;
  for (int z=0; z<SK; z++) s += Part[(size_t)z*MN + i];
  if (EPI==2) s += aux[i];
  Out[i] = s;
}

// ---------------- causal depthwise conv (width 4) + bias + silu ----------------
__global__ void conv_k(const float* __restrict__ xz, const float* __restrict__ cw,
                       const float* __restrict__ cb, float* __restrict__ xc)
{
  const int d = blockIdx.x*256 + threadIdx.x;
  const int g = blockIdx.y;
  const int b = g >> 9, t = g & (SEQL-1);
  float4 w4 = *(const float4*)(cw + (size_t)d*4);
  const float wk[4] = {w4.x, w4.y, w4.z, w4.w};
  const float* col = xz + ((size_t)b*SEQL)*(2*DI) + d;
  float acc = cb[d];
  #pragma unroll
  for (int k=0;k<4;k++){
    int tt = t - 3 + k;
    if (tt >= 0) acc = fmaf(wk[k], col[(size_t)tt*(2*DI)], acc);
  }
  xc[(size_t)g*DI + d] = silu_(acc);
}

// ---------------- pass 1: per-chunk v aggregates + chunk dt sums ----------------
__global__ void vagg_k(const float* __restrict__ dt, const float* __restrict__ xcp,
                       const float* __restrict__ xdbl, float* __restrict__ Vagg,
                       float* __restrict__ S, int C, int T)
{
  const int d = blockIdx.x*256 + threadIdx.x;
  const int c = blockIdx.y, b = blockIdx.z;
  float acc[16];
  #pragma unroll
  for (int n=0;n<16;n++) acc[n] = 0.f;
  float sdt = 0.f;
  for (int s=0;s<T;s++){
    const int g = b*SEQL + c*T + s;
    float dv = dt[(size_t)g*DI + d];
    float w  = dv * xcp[(size_t)g*DI + d];
    sdt += dv;
    #pragma unroll
    for (int n=0;n<16;n++) acc[n] = fmaf(BETA, acc[n], w * xdbl[(size_t)g*XDC + 48 + n]);
  }
  const size_t base = ((size_t)(b*C + c)*NDS)*DI + d;
  #pragma unroll
  for (int n=0;n<16;n++) Vagg[base + (size_t)n*DI] = acc[n];
  S[(size_t)(b*C + c)*DI + d] = sdt;
}

// ---------------- pass 2: sequential-over-chunks combine for v_start ----------------
__global__ void vcomb_k(const float* __restrict__ Vagg, float* __restrict__ vst,
                        int C, float betaT)
{
  const int d = blockIdx.x*256 + threadIdx.x;
  const int n = blockIdx.y, b = blockIdx.z;
  const size_t stride = (size_t)NDS*DI;
  size_t idx = ((size_t)(b*C)*NDS + n)*DI + d;
  float v = 0.f;
  for (int c=0;c<C;c++){
    vst[idx] = v;
    v = fmaf(betaT, v, Vagg[idx]);
    idx += stride;
  }
}

// ---------------- pass 3: in-chunk scan with Newton-Schulz, state in registers ----------------
// thread owns d = tid, tid+512, tid+1024 ; NS: u = v*(aI+bS+cS^2)/nu, S=R/nu^2, nu=sqrt(tr R)+1e-7
__global__ __launch_bounds__(512) void scan_k(
    const float* __restrict__ vst, const float* __restrict__ dt,
    const float* __restrict__ xcp, const float* __restrict__ xdbl,
    const float* __restrict__ A_log,
    float* __restrict__ ylocal, float* __restrict__ hend,
    int C, int T)
{
  const int c = blockIdx.x, b = blockIdx.y;
  const int tid = threadIdx.x;
  const int lane = tid & 63;
  const int wid = tid >> 6;
  __shared__ float ldsR[16][136];
  __shared__ float Rmat[16][16];
  __shared__ float Qmat[16][16];

  // pair (pi,pj) for tid<136 (upper triangle incl diag)
  int pi = 0, pj = 0;
  if (tid < 136){
    int pp = tid;
    while (pp >= 16 - pi){ pp -= 16 - pi; pi++; }
    pj = pi + pp;
  }

  float v[3][16], h[3][16], Ar[3][16];
  #pragma unroll
  for (int j=0;j<3;j++){
    const float* arow = A_log + (size_t)(tid + j*512)*NDS;
    #pragma unroll
    for (int n=0;n<16;n++) Ar[j][n] = -__expf(arow[n]);
  }
  {
    const float* vs = vst + ((size_t)(b*C + c)*NDS)*DI;
    #pragma unroll
    for (int j=0;j<3;j++)
      #pragma unroll
      for (int n=0;n<16;n++) v[j][n] = vs[(size_t)n*DI + tid + j*512];
  }
  #pragma unroll
  for (int j=0;j<3;j++)
    #pragma unroll
    for (int n=0;n<16;n++) h[j][n] = 0.f;

  const int t0 = c*T;
  for (int s=0; s<T; s++){
    const int g = b*SEQL + t0 + s;
    // phase A: v <- beta*v + (dt*xc) outer B
    float dtv[3];
    float Bv[16];
    #pragma unroll
    for (int n=0;n<16;n++) Bv[n] = xdbl[(size_t)g*XDC + 48 + n];
    #pragma unroll
    for (int j=0;j<3;j++){
      dtv[j] = dt[(size_t)g*DI + tid + j*512];
      float w = dtv[j] * xcp[(size_t)g*DI + tid + j*512];
      #pragma unroll
      for (int n=0;n<16;n++) v[j][n] = fmaf(BETA, v[j][n], w*Bv[n]);
    }
    // R = v^T v : per-thread partials over 3 rows, half-wave butterfly, LDS slots
    {
      int p = 0;
      #pragma unroll
      for (int i2=0;i2<16;i2++){
        #pragma unroll
        for (int j2=i2;j2<16;j2++){
          float sR = v[0][i2]*v[0][j2];
          sR = fmaf(v[1][i2], v[1][j2], sR);
          sR = fmaf(v[2][i2], v[2][j2], sR);
          sR += __shfl_xor(sR, 1);
          sR += __shfl_xor(sR, 2);
          sR += __shfl_xor(sR, 4);
          sR += __shfl_xor(sR, 8);
          sR += __shfl_xor(sR, 16);
          if ((lane & 31) == 0) ldsR[(wid<<1) | (lane>>5)][p] = sR;
          p++;
        }
      }
    }
    __syncthreads();
    float rp = 0.f;
    if (tid < 136){
      #pragma unroll
      for (int w2=0; w2<16; w2++) rp += ldsR[w2][tid];
      Rmat[pi][pj] = rp; Rmat[pj][pi] = rp;
    }
    __syncthreads();
    float tr = 0.f;
    #pragma unroll
    for (int i2=0;i2<16;i2++) tr += Rmat[i2][i2];
    const float nu = sqrtf(tr) + 1e-7f;
    const float inv_nu = 1.f/nu;
    const float inv2 = inv_nu*inv_nu;
    const float inv4 = inv2*inv2;
    if (tid < 136){
      float a2 = 0.f;
      #pragma unroll
      for (int k=0;k<16;k++) a2 = fmaf(Rmat[pi][k], Rmat[k][pj], a2);
      float q = NSB*inv2*rp + NSC*inv4*a2;
      if (pi == pj) q += NSA;
      Qmat[pi][pj] = q; Qmat[pj][pi] = q;
    }
    __syncthreads();
    // phase E: u = v*Q/nu ; h = exp(dt*A) h + u ; y = h . C_t
    float yv[3] = {0.f, 0.f, 0.f};
    #pragma unroll
    for (int n=0;n<16;n++){
      float a0=0.f, a1=0.f, a2v=0.f;
      #pragma unroll
      for (int k=0;k<16;k++){
        float q = Qmat[k][n];
        a0 = fmaf(v[0][k], q, a0);
        a1 = fmaf(v[1][k], q, a1);
        a2v = fmaf(v[2][k], q, a2v);
      }
      const float Cn = xdbl[(size_t)g*XDC + 64 + n];
      float acc3[3] = {a0, a1, a2v};
      #pragma unroll
      for (int j=0;j<3;j++){
        float e = __expf(dtv[j]*Ar[j][n]);
        h[j][n] = fmaf(e, h[j][n], acc3[j]*inv_nu);
        yv[j] = fmaf(h[j][n], Cn, yv[j]);
      }
    }
    ylocal[(size_t)g*DI + tid]        = yv[0];
    ylocal[(size_t)g*DI + tid + 512]  = yv[1];
    ylocal[(size_t)g*DI + tid + 1024] = yv[2];
  }
  float* he = hend + ((size_t)(b*C + c)*NDS)*DI;
  #pragma unroll
  for (int j=0;j<3;j++)
    #pragma unroll
    for (int n=0;n<16;n++) he[(size_t)n*DI + tid + j*512] = h[j][n];
}

// ---------------- pass 4: combine h chunk-starts (prod of dA = exp(A*sum dt)) ----------------
__global__ void hcomb_k(const float* __restrict__ hend, const float* __restrict__ S,
                        const float* __restrict__ A_log, float* __restrict__ hst, int C)
{
  const int d = blockIdx.x*256 + threadIdx.x;
  const int n = blockIdx.y, b = blockIdx.z;
  const float An = -__expf(A_log[(size_t)d*NDS + n]);
  const size_t stride = (size_t)NDS*DI;
  size_t idx  = ((size_t)(b*C)*NDS + n)*DI + d;
  size_t sidx = (size_t)(b*C)*DI + d;
  float hv = 0.f;
  for (int c=0;c<C;c++){
    hst[idx] = hv;
    hv = fmaf(__expf(An * S[sidx]), hv, hend[idx]);
    idx += stride; sidx += DI;
  }
}

// ---------------- pass 5: y = (ylocal + boundary corr + D*xc) * silu(z), into xz[:, :DI] ----------------
__global__ void yepi_k(const float* __restrict__ ylocal, const float* __restrict__ hst,
                       const float* __restrict__ dt, const float* __restrict__ xdbl,
                       const float* __restrict__ A_log, const float* __restrict__ Dv,
                       const float* __restrict__ xcp, float* __restrict__ xz,
                       int C, int T)
{
  const int d = blockIdx.x*256 + threadIdx.x;
  const int g = blockIdx.y;
  const int b = g >> 9, t = g & (SEQL-1);
  const int c = t / T, s0 = c*T;
  float ddt = 0.f;
  for (int r=s0; r<=t; r++) ddt += dt[(size_t)(b*SEQL + r)*DI + d];
  const float* hs = hst + ((size_t)(b*C + c)*NDS)*DI + d;
  const float* ar = A_log + (size_t)d*NDS;
  float corr = 0.f;
  #pragma unroll
  for (int n=0;n<16;n++){
    float An = -__expf(ar[n]);
    float Cn = xdbl[(size_t)g*XDC + 64 + n];
    corr = fmaf(hs[(size_t)n*DI] * __expf(An*ddt), Cn, corr);
  }
  float y = ylocal[(size_t)g*DI + d] + corr + Dv[d]*xcp[(size_t)g*DI + d];
  float z = xz[(size_t)g*(2*DI) + DI + d];
  xz[(size_t)g*(2*DI) + d] = y * silu_(z);   // overwrite dead xi half; out_proj reads lda=2*DI
}

// ============================== host ==============================
extern "C" void kernel_launch(void* const* d_in, const int* in_sizes, int n_in,
                              void* d_out, int out_size, void* d_ws, size_t ws_size,
                              hipStream_t stream)
{
  (void)in_sizes; (void)n_in; (void)out_size;
  const float* x      = (const float*)d_in[0];
  const float* in_w   = (const float*)d_in[1];
  const float* conv_w = (const float*)d_in[2];
  const float* conv_b = (const float*)d_in[3];
  const float* xp_w   = (const float*)d_in[4];
  const float* dtp_w  = (const float*)d_in[5];
  const float* dtp_b  = (const float*)d_in[6];
  const float* A_log  = (const float*)d_in[7];
  const float* Dp     = (const float*)d_in[8];
  const float* out_w  = (const float*)d_in[9];
  const float* norm_w = (const float*)d_in[10];
  const float* fnorm  = (const float*)d_in[11];

  const size_t nf = ws_size / sizeof(float);
  auto needf = [](int C, bool wantPart)->size_t{
    size_t fixed = (size_t)3*NT*DM + (size_t)NT*2*DI + (size_t)3*NT*DI + (size_t)NT*XDC;
    size_t cdep  = (size_t)NB*C*DI + (size_t)2*NB*C*NDS*DI;
    size_t p     = wantPart ? (size_t)4*NT*DM : 0;  // max partial: out_proj SK=4
    return fixed + cdep + p + 2048;
  };
  int C; bool part = true;
  if      (needf(128, true) <= nf) C = 128;
  else if (needf(64,  true) <= nf) C = 64;
  else if (needf(32,  true) <= nf) C = 32;
  else { C = 32; part = false; }
  const int T = SEQL / C;
  const float betaT = powf(BETA, (float)T);
  const int skx = part ? 8 : 1, skout = part ? 4 : 1;

  float* w0 = (float*)d_ws; size_t off = 0;
  auto alloc = [&](size_t n)->float*{ float* p = w0 + off; off += (n + 63) & ~(size_t)63; return p; };
  float* xa     = alloc((size_t)NT*DM);
  float* xb     = alloc((size_t)NT*DM);
  float* xn     = alloc((size_t)NT*DM);
  float* xz     = alloc((size_t)NT*2*DI);
  float* xcb    = alloc((size_t)NT*DI);
  float* xdbl   = alloc((size_t)NT*XDC);
  float* dtb    = alloc((size_t)NT*DI);
  float* ylocal = alloc((size_t)NT*DI);
  float* Sbuf   = alloc((size_t)NB*C*DI);
  float* big1   = alloc((size_t)NB*C*NDS*DI);   // Vagg, later h_end
  float* big2   = alloc((size_t)NB*C*NDS*DI);   // v_start, later h_start
  float* partb  = part ? alloc((size_t)4*NT*DM) : (float*)d_ws;

  const float* xcur = x;
  float* nxt = xa;
  for (int l=0; l<2; l++){
    const float* inw_l = in_w   + (size_t)l*2*DI*DM;
    const float* cw_l  = conv_w + (size_t)l*DI*4;
    const float* cb_l  = conv_b + (size_t)l*DI;
    const float* xpw_l = xp_w   + (size_t)l*XDC*DI;
    const float* dtw_l = dtp_w  + (size_t)l*DI*DTR;
    const float* dtbi  = dtp_b  + (size_t)l*DI;
    const float* al_l  = A_log  + (size_t)l*DI*NDS;
    const float* d_l   = Dp     + (size_t)l*DI;
    const float* ow_l  = out_w  + (size_t)l*DM*DI;
    const float* nw_l  = norm_w + (size_t)l*DM;

    rms_k<<<dim3(NT), dim3(256), 0, stream>>>(xcur, nw_l, xn);
    gemm128<0><<<dim3(2*DI/128, NT/128, 1), dim3(256), 0, stream>>>(
        xn, DM, inw_l, DM, xz, partb, nullptr, NT, 2*DI, DM, 1);
    conv_k<<<dim3(DI/256, NT), dim3(256), 0, stream>>>(xz, cw_l, cb_l, xcb);
    gemm64<0><<<dim3((XDC+63)/64, NT/64, skx), dim3(256), 0, stream>>>(
        xcb, DI, xpw_l, DI, xdbl, partb, nullptr, NT, XDC, DI, skx);
    if (skx > 1)
      reduce_k<0><<<dim3((NT*XDC+255)/256), dim3(256), 0, stream>>>(partb, xdbl, nullptr, NT*XDC, skx);
    gemm128<1><<<dim3(DI/128, NT/128, 1), dim3(256), 0, stream>>>(
        xdbl, XDC, dtw_l, DTR, dtb, partb, dtbi, NT, DI, DTR, 1);
    vagg_k<<<dim3(DI/256, C, NB), dim3(256), 0, stream>>>(dtb, xcb, xdbl, big1, Sbuf, C, T);
    vcomb_k<<<dim3(DI/256, NDS, NB), dim3(256), 0, stream>>>(big1, big2, C, betaT);
    scan_k<<<dim3(C, NB), dim3(512), 0, stream>>>(big2, dtb, xcb, xdbl, al_l, ylocal, big1, C, T);
    hcomb_k<<<dim3(DI/256, NDS, NB), dim3(256), 0, stream>>>(big1, Sbuf, al_l, big2, C);
    yepi_k<<<dim3(DI/256, NT), dim3(256), 0, stream>>>(ylocal, big2, dtb, xdbl, al_l, d_l, xcb, xz, C, T);
    gemm128<2><<<dim3(DM/128, NT/128, skout), dim3(256), 0, stream>>>(
        xz, 2*DI, ow_l, DI, nxt, partb, xcur, NT, DM, DI, skout);
    if (skout > 1)
      reduce_k<2><<<dim3((NT*DM+255)/256), dim3(256), 0, stream>>>(partb, nxt, xcur, NT*DM, skout);
    xcur = nxt; nxt = xb;
  }
  rms_k<<<dim3(NT), dim3(256), 0, stream>>>(xcur, fnorm, (float*)d_out);
}

// Round 2
// 762.012 us; speedup vs baseline: 1.3111x; 1.3111x over previous
//
#include <hip/hip_runtime.h>
#include <math.h>

#define DM   768
#define DI   1536
#define NDS  16
#define DTR  48
#define XDC  80
#define NB   2
#define SEQL 512
#define NT   (NB*SEQL)
#define BETA 0.9f
#define NSA  3.4445f
#define NSB  (-4.775f)
#define NSC  2.0315f
#define LOG2E 1.4426950408889634f

__device__ __forceinline__ float silu_(float x){ return x / (1.f + __expf(-x)); }

// ---------------- rmsnorm: one block per token ----------------
__global__ void rms_k(const float* __restrict__ X, const float* __restrict__ W,
                      float* __restrict__ O)
{
  const int g = blockIdx.x, tid = threadIdx.x;
  const float* xr = X + (size_t)g*DM;
  float x0 = xr[tid], x1 = xr[tid+256], x2 = xr[tid+512];
  float ss = x0*x0 + x1*x1 + x2*x2;
  #pragma unroll
  for (int m=1; m<=32; m<<=1) ss += __shfl_xor(ss, m);
  __shared__ float ws[4];
  if ((tid & 63) == 0) ws[tid>>6] = ss;
  __syncthreads();
  float sc = rsqrtf((ws[0]+ws[1]+ws[2]+ws[3])*(1.f/DM) + 1e-5f);
  float* o = O + (size_t)g*DM;
  o[tid]     = x0*sc*W[tid];
  o[tid+256] = x1*sc*W[tid+256];
  o[tid+512] = x2*sc*W[tid+512];
}

// ---------------- GEMM: C[r,c] = sum_k A[r*lda+k]*B[c*ldb+k] ----------------
// EPI: 0 none, 1 softplus(x+bias[col]), 2 x+res[r*N+c].  K split over blockIdx.z.
template<int EPI>
__global__ void gemm128(const float* __restrict__ A, int lda,
                        const float* __restrict__ Bw, int ldb,
                        float* __restrict__ Out, float* __restrict__ Part,
                        const float* __restrict__ aux,
                        int M, int N, int K, int SK)
{
  __shared__ float As[16][128], Bs[16][128];
  const int tid = threadIdx.x;
  const int bm = blockIdx.y*128, bn = blockIdx.x*128;
  const int kc = K/SK, kBeg = blockIdx.z*kc, kEnd = kBeg + kc;
  const int lr = tid>>1, lk = (tid&1)<<3;
  const int tx = tid&15, ty = tid>>4;
  float acc[8][8];
  #pragma unroll
  for (int i=0;i<8;i++)
    #pragma unroll
    for (int j=0;j<8;j++) acc[i][j] = 0.f;
  const float* Ap = A + (size_t)(bm+lr)*lda + lk;
  const bool bok = (bn+lr) < N;
  const float* Bp = Bw + (size_t)(bn+lr)*ldb + lk;
  for (int k0=kBeg; k0<kEnd; k0+=16){
    float4 a0 = *(const float4*)(Ap + k0);
    float4 a1 = *(const float4*)(Ap + k0 + 4);
    float4 b0 = {0,0,0,0}, b1 = {0,0,0,0};
    if (bok){ b0 = *(const float4*)(Bp + k0); b1 = *(const float4*)(Bp + k0 + 4); }
    __syncthreads();
    As[lk+0][lr]=a0.x; As[lk+1][lr]=a0.y; As[lk+2][lr]=a0.z; As[lk+3][lr]=a0.w;
    As[lk+4][lr]=a1.x; As[lk+5][lr]=a1.y; As[lk+6][lr]=a1.z; As[lk+7][lr]=a1.w;
    Bs[lk+0][lr]=b0.x; Bs[lk+1][lr]=b0.y; Bs[lk+2][lr]=b0.z; Bs[lk+3][lr]=b0.w;
    Bs[lk+4][lr]=b1.x; Bs[lk+5][lr]=b1.y; Bs[lk+6][lr]=b1.z; Bs[lk+7][lr]=b1.w;
    __syncthreads();
    #pragma unroll
    for (int kk=0;kk<16;kk++){
      float a[8], b[8];
      *(float4*)&a[0] = *(const float4*)&As[kk][ty*4];
      *(float4*)&a[4] = *(const float4*)&As[kk][64+ty*4];
      *(float4*)&b[0] = *(const float4*)&Bs[kk][tx*4];
      *(float4*)&b[4] = *(const float4*)&Bs[kk][64+tx*4];
      #pragma unroll
      for (int i=0;i<8;i++)
        #pragma unroll
        for (int j=0;j<8;j++) acc[i][j] = fmaf(a[i], b[j], acc[i][j]);
    }
  }
  #pragma unroll
  for (int i=0;i<8;i++){
    const int row = bm + ((i<4) ? ty*4+i : 64+ty*4+i-4);
    #pragma unroll
    for (int j=0;j<8;j++){
      const int col = bn + ((j<4) ? tx*4+j : 64+tx*4+j-4);
      if (col < N){
        if (SK == 1){
          float vv = acc[i][j];
          if (EPI==1){ vv += aux[col]; vv = fmaxf(vv,0.f) + log1pf(__expf(-fabsf(vv))); }
          if (EPI==2){ vv += aux[(size_t)row*N+col]; }
          Out[(size_t)row*N+col] = vv;
        } else {
          Part[(size_t)blockIdx.z*M*N + (size_t)row*N+col] = acc[i][j];
        }
      }
    }
  }
}

template<int EPI>
__global__ void gemm64(const float* __restrict__ A, int lda,
                       const float* __restrict__ Bw, int ldb,
                       float* __restrict__ Out, float* __restrict__ Part,
                       const float* __restrict__ aux,
                       int M, int N, int K, int SK)
{
  __shared__ float As[16][64], Bs[16][64];
  const int tid = threadIdx.x;
  const int bm = blockIdx.y*64, bn = blockIdx.x*64;
  const int kc = K/SK, kBeg = blockIdx.z*kc, kEnd = kBeg + kc;
  const int lr = tid>>2, lk = (tid&3)<<2;
  const int tx = tid&15, ty = tid>>4;
  float acc[4][4];
  #pragma unroll
  for (int i=0;i<4;i++)
    #pragma unroll
    for (int j=0;j<4;j++) acc[i][j] = 0.f;
  const float* Ap = A + (size_t)(bm+lr)*lda + lk;
  const bool bok = (bn+lr) < N;
  const float* Bp = Bw + (size_t)(bn+lr)*ldb + lk;
  for (int k0=kBeg; k0<kEnd; k0+=16){
    float4 a0 = *(const float4*)(Ap + k0);
    float4 b0 = {0,0,0,0};
    if (bok) b0 = *(const float4*)(Bp + k0);
    __syncthreads();
    As[lk+0][lr]=a0.x; As[lk+1][lr]=a0.y; As[lk+2][lr]=a0.z; As[lk+3][lr]=a0.w;
    Bs[lk+0][lr]=b0.x; Bs[lk+1][lr]=b0.y; Bs[lk+2][lr]=b0.z; Bs[lk+3][lr]=b0.w;
    __syncthreads();
    #pragma unroll
    for (int kk=0;kk<16;kk++){
      float a[4], b[4];
      *(float4*)a = *(const float4*)&As[kk][ty*4];
      *(float4*)b = *(const float4*)&Bs[kk][tx*4];
      #pragma unroll
      for (int i=0;i<4;i++)
        #pragma unroll
        for (int j=0;j<4;j++) acc[i][j] = fmaf(a[i], b[j], acc[i][j]);
    }
  }
  #pragma unroll
  for (int i=0;i<4;i++){
    const int row = bm + ty*4 + i;
    #pragma unroll
    for (int j=0;j<4;j++){
      const int col = bn + tx*4 + j;
      if (col < N){
        if (SK == 1){
          float vv = acc[i][j];
          if (EPI==1){ vv += aux[col]; vv = fmaxf(vv,0.f) + log1pf(__expf(-fabsf(vv))); }
          if (EPI==2){ vv += aux[(size_t)row*N+col]; }
          Out[(size_t)row*N+col] = vv;
        } else {
          Part[(size_t)blockIdx.z*M*N + (size_t)row*N+col] = acc[i][j];
        }
      }
    }
  }
}

template<int EPI>
__global__ void reduce_k(const float* __restrict__ Part, float* __restrict__ Out,
                         const float* __restrict__ aux, int MN, int SK)
{
  const int i = blockIdx.x*256 + threadIdx.x;
  if (i >= MN) return;
  float s = 0.f;
  for (int z=0; z<SK; z++) s += Part[(size_t)z*MN + i];
  if (EPI==2) s += aux[i];
  Out[i] = s;
}

// ---------------- causal depthwise conv (width 4) + bias + silu ----------------
__global__ void conv_k(const float* __restrict__ xz, const float* __restrict__ cw,
                       const float* __restrict__ cb, float* __restrict__ xc)
{
  const int d = blockIdx.x*256 + threadIdx.x;
  const int g = blockIdx.y;
  const int b = g >> 9, t = g & (SEQL-1);
  float4 w4 = *(const float4*)(cw + (size_t)d*4);
  const float wk[4] = {w4.x, w4.y, w4.z, w4.w};
  const float* col = xz + ((size_t)b*SEQL)*(2*DI) + d;
  float acc = cb[d];
  #pragma unroll
  for (int k=0;k<4;k++){
    int tt = t - 3 + k;
    if (tt >= 0) acc = fmaf(wk[k], col[(size_t)tt*(2*DI)], acc);
  }
  xc[(size_t)g*DI + d] = silu_(acc);
}

// ---------------- pass 1: per-chunk v aggregates + chunk dt sums ----------------
__global__ void vagg_k(const float* __restrict__ dt, const float* __restrict__ xcp,
                       const float* __restrict__ xdbl, float* __restrict__ Vagg,
                       float* __restrict__ S, int C, int T)
{
  const int d = blockIdx.x*256 + threadIdx.x;
  const int c = blockIdx.y, b = blockIdx.z;
  float acc[16];
  #pragma unroll
  for (int n=0;n<16;n++) acc[n] = 0.f;
  float sdt = 0.f;
  for (int s=0;s<T;s++){
    const int g = b*SEQL + c*T + s;
    float dv = dt[(size_t)g*DI + d];
    float w  = dv * xcp[(size_t)g*DI + d];
    sdt += dv;
    #pragma unroll
    for (int n=0;n<16;n++) acc[n] = fmaf(BETA, acc[n], w * xdbl[(size_t)g*XDC + 48 + n]);
  }
  const size_t base = ((size_t)(b*C + c)*NDS)*DI + d;
  #pragma unroll
  for (int n=0;n<16;n++) Vagg[base + (size_t)n*DI] = acc[n];
  S[(size_t)(b*C + c)*DI + d] = sdt;
}

// ---------------- pass 2: sequential-over-chunks combine for v_start ----------------
__global__ void vcomb_k(const float* __restrict__ Vagg, float* __restrict__ vst,
                        int C, float betaT)
{
  const int d = blockIdx.x*256 + threadIdx.x;
  const int n = blockIdx.y, b = blockIdx.z;
  const size_t stride = (size_t)NDS*DI;
  size_t idx = ((size_t)(b*C)*NDS + n)*DI + d;
  float v = 0.f;
  for (int c=0;c<C;c++){
    vst[idx] = v;
    v = fmaf(betaT, v, Vagg[idx]);
    idx += stride;
  }
}

// ---------------- pass 3: in-chunk scan with Newton-Schulz ----------------
// thread owns d = tid, tid+512, tid+1024.
// R_t = v_t^T v_t maintained by exact rank-2 recurrence:
//   v_t = beta*v_{t-1} + w b^T  =>  R_t = b2*R + beta*(p b^T + b p^T) + s*b b^T
//   p = v_{t-1}^T w (16 reduce),  s = w^T w (1 reduce)
// NS: u = v*(aI + b'S + c'S^2)/nu, S = R/nu^2, nu = sqrt(tr R)+1e-7
__global__ __launch_bounds__(512,2) void scan_k(
    const float* __restrict__ vst, const float* __restrict__ dt,
    const float* __restrict__ xcp, const float* __restrict__ xdbl,
    const float* __restrict__ A_log,
    float* __restrict__ ylocal, float* __restrict__ hend,
    int C, int T)
{
  const int c = blockIdx.x, b = blockIdx.y;
  const int tid = threadIdx.x;
  const int lane = tid & 63;
  const int wid = tid >> 6;
  __shared__ float Rmat[16][17];
  __shared__ float Qmat[16][17];
  __shared__ float red[8][20];
  __shared__ float sBC[2][32];
  __shared__ float gram[32][136];

  // pair (pi,pj) for tid<136 (upper triangle incl diag)
  int pi = 0, pj = 0;
  if (tid < 136){
    int pp = tid;
    while (pp >= 16 - pi){ pp -= 16 - pi; pi++; }
    pj = pi + pp;
  }

  float v[3][16];
  {
    const float* vs = vst + ((size_t)(b*C + c)*NDS)*DI;
    #pragma unroll
    for (int j=0;j<3;j++)
      #pragma unroll
      for (int n=0;n<16;n++) v[j][n] = vs[(size_t)n*DI + tid + j*512];
  }

  // ---- chunk-start Gram: R_start = vst^T vst (exact, once) ----
  {
    int p = 0;
    #pragma unroll
    for (int i2=0;i2<16;i2++){
      #pragma unroll
      for (int j2=i2;j2<16;j2++){
        float sR = v[0][i2]*v[0][j2];
        sR = fmaf(v[1][i2], v[1][j2], sR);
        sR = fmaf(v[2][i2], v[2][j2], sR);
        sR += __shfl_xor(sR, 1);
        sR += __shfl_xor(sR, 2);
        sR += __shfl_xor(sR, 4);
        sR += __shfl_xor(sR, 8);
        if ((lane & 15) == (p & 15)) gram[(wid<<2) | (lane>>4)][p] = sR;
        p++;
      }
    }
  }
  __syncthreads();
  if (tid < 136){
    float r = 0.f;
    #pragma unroll
    for (int q=0;q<32;q++) r += gram[q][tid];
    Rmat[pi][pj] = r; Rmat[pj][pi] = r;
  }

  float h[3][16], Ar[3][16];
  #pragma unroll
  for (int j=0;j<3;j++){
    const float* arow = A_log + (size_t)(tid + j*512)*NDS;
    #pragma unroll
    for (int n=0;n<16;n++){
      Ar[j][n] = -__expf(arow[n]) * LOG2E;   // pre-scaled for exp2f
      h[j][n] = 0.f;
    }
  }

  const int t0 = c*T;
  for (int s=0; s<T; s++){
    const int g = b*SEQL + t0 + s;
    const int par = s & 1;
    if (tid < 32) sBC[par][tid] = xdbl[(size_t)g*XDC + 48 + tid];
    float dtv[3], w3[3];
    #pragma unroll
    for (int j=0;j<3;j++){
      dtv[j] = dt[(size_t)g*DI + tid + j*512];
      w3[j]  = dtv[j] * xcp[(size_t)g*DI + tid + j*512];
    }
    // 17 block-reductions: p[16] (uses v_{t-1}) and s = w.w
    float ps[17];
    #pragma unroll
    for (int n=0;n<16;n++){
      float t1 = v[0][n]*w3[0];
      t1 = fmaf(v[1][n], w3[1], t1);
      ps[n] = fmaf(v[2][n], w3[2], t1);
    }
    ps[16] = w3[0]*w3[0] + w3[1]*w3[1] + w3[2]*w3[2];
    #pragma unroll
    for (int m=1; m<=32; m<<=1){
      #pragma unroll
      for (int k=0;k<17;k++) ps[k] += __shfl_xor(ps[k], m);
    }
    if (lane == 0){
      #pragma unroll
      for (int k=0;k<17;k++) red[wid][k] = ps[k];
    }
    __syncthreads();                       // S1: red + sBC ready
    // v update (needs B from sBC)
    #pragma unroll
    for (int j=0;j<3;j++)
      #pragma unroll
      for (int n=0;n<16;n++) v[j][n] = fmaf(BETA, v[j][n], w3[j]*sBC[par][n]);
    if (tid < 136){
      float p_i=0.f, p_j=0.f, sw=0.f;
      #pragma unroll
      for (int q=0;q<8;q++){ p_i += red[q][pi]; p_j += red[q][pj]; sw += red[q][16]; }
      const float bi = sBC[par][pi], bj = sBC[par][pj];
      float rn = BETA*BETA*Rmat[pi][pj];
      rn = fmaf(BETA, p_i*bj + bi*p_j, rn);
      rn = fmaf(sw, bi*bj, rn);
      Rmat[pi][pj] = rn; if (pi != pj) Rmat[pj][pi] = rn;
    }
    __syncthreads();                       // S2: Rmat ready
    float tr = 0.f;
    #pragma unroll
    for (int i2=0;i2<16;i2++) tr += Rmat[i2][i2];
    const float nu = sqrtf(tr) + 1e-7f;
    const float inv_nu = 1.f/nu;
    const float inv2 = inv_nu*inv_nu;
    const float inv4 = inv2*inv2;
    if (tid < 136){
      float a2 = 0.f;
      #pragma unroll
      for (int k=0;k<16;k++) a2 = fmaf(Rmat[pi][k], Rmat[k][pj], a2);
      float q = NSB*inv2*Rmat[pi][pj] + NSC*inv4*a2;
      if (pi == pj) q += NSA;
      Qmat[pi][pj] = q; if (pi != pj) Qmat[pj][pi] = q;
    }
    __syncthreads();                       // S3: Qmat ready
    // u = v*Q/nu ; h = exp2(dt*Ar) h + u ; y = h . C_t
    float yv[3] = {0.f, 0.f, 0.f};
    #pragma unroll
    for (int n=0;n<16;n++){
      float a0=0.f, a1=0.f, a2v=0.f;
      #pragma unroll
      for (int k=0;k<16;k++){
        const float q = Qmat[k][n];
        a0  = fmaf(v[0][k], q, a0);
        a1  = fmaf(v[1][k], q, a1);
        a2v = fmaf(v[2][k], q, a2v);
      }
      const float Cn = sBC[par][16+n];
      float acc3[3] = {a0, a1, a2v};
      #pragma unroll
      for (int j=0;j<3;j++){
        const float e = exp2f(dtv[j]*Ar[j][n]);
        h[j][n] = fmaf(e, h[j][n], acc3[j]*inv_nu);
        yv[j] = fmaf(h[j][n], Cn, yv[j]);
      }
    }
    ylocal[(size_t)g*DI + tid]        = yv[0];
    ylocal[(size_t)g*DI + tid + 512]  = yv[1];
    ylocal[(size_t)g*DI + tid + 1024] = yv[2];
  }
  float* he = hend + ((size_t)(b*C + c)*NDS)*DI;
  #pragma unroll
  for (int j=0;j<3;j++)
    #pragma unroll
    for (int n=0;n<16;n++) he[(size_t)n*DI + tid + j*512] = h[j][n];
}

// ---------------- pass 4: combine h chunk-starts (prod of dA = exp(A*sum dt)) ----------------
__global__ void hcomb_k(const float* __restrict__ hend, const float* __restrict__ S,
                        const float* __restrict__ A_log, float* __restrict__ hst, int C)
{
  const int d = blockIdx.x*256 + threadIdx.x;
  const int n = blockIdx.y, b = blockIdx.z;
  const float An = -__expf(A_log[(size_t)d*NDS + n]);
  const size_t stride = (size_t)NDS*DI;
  size_t idx  = ((size_t)(b*C)*NDS + n)*DI + d;
  size_t sidx = (size_t)(b*C)*DI + d;
  float hv = 0.f;
  for (int c=0;c<C;c++){
    hst[idx] = hv;
    hv = fmaf(__expf(An * S[sidx]), hv, hend[idx]);
    idx += stride; sidx += DI;
  }
}

// ---------------- pass 5: y = (ylocal + boundary corr + D*xc) * silu(z) ----------------
__global__ void yepi_k(const float* __restrict__ ylocal, const float* __restrict__ hst,
                       const float* __restrict__ dt, const float* __restrict__ xdbl,
                       const float* __restrict__ A_log, const float* __restrict__ Dv,
                       const float* __restrict__ xcp, float* __restrict__ xz,
                       int C, int T)
{
  const int d = blockIdx.x*256 + threadIdx.x;
  const int g = blockIdx.y;
  const int b = g >> 9, t = g & (SEQL-1);
  const int c = t / T, s0 = c*T;
  float ddt = 0.f;
  for (int r=s0; r<=t; r++) ddt += dt[(size_t)(b*SEQL + r)*DI + d];
  const float* hs = hst + ((size_t)(b*C + c)*NDS)*DI + d;
  const float* ar = A_log + (size_t)d*NDS;
  float corr = 0.f;
  #pragma unroll
  for (int n=0;n<16;n++){
    float An = -__expf(ar[n]);
    float Cn = xdbl[(size_t)g*XDC + 64 + n];
    corr = fmaf(hs[(size_t)n*DI] * __expf(An*ddt), Cn, corr);
  }
  float y = ylocal[(size_t)g*DI + d] + corr + Dv[d]*xcp[(size_t)g*DI + d];
  float z = xz[(size_t)g*(2*DI) + DI + d];
  xz[(size_t)g*(2*DI) + d] = y * silu_(z);   // overwrite dead xi half; out_proj reads lda=2*DI
}

// ============================== host ==============================
extern "C" void kernel_launch(void* const* d_in, const int* in_sizes, int n_in,
                              void* d_out, int out_size, void* d_ws, size_t ws_size,
                              hipStream_t stream)
{
  (void)in_sizes; (void)n_in; (void)out_size; (void)ws_size;
  const float* x      = (const float*)d_in[0];
  const float* in_w   = (const float*)d_in[1];
  const float* conv_w = (const float*)d_in[2];
  const float* conv_b = (const float*)d_in[3];
  const float* xp_w   = (const float*)d_in[4];
  const float* dtp_w  = (const float*)d_in[5];
  const float* dtp_b  = (const float*)d_in[6];
  const float* A_log  = (const float*)d_in[7];
  const float* Dp     = (const float*)d_in[8];
  const float* out_w  = (const float*)d_in[9];
  const float* norm_w = (const float*)d_in[10];
  const float* fnorm  = (const float*)d_in[11];

  const int C = 128, T = SEQL / C;
  const float betaT = powf(BETA, (float)T);
  const int skin = 4, skx = 8, skout = 16;

  float* w0 = (float*)d_ws; size_t off = 0;
  auto alloc = [&](size_t n)->float*{ float* p = w0 + off; off += (n + 63) & ~(size_t)63; return p; };
  float* xa     = alloc((size_t)NT*DM);
  float* xb     = alloc((size_t)NT*DM);
  float* xn     = alloc((size_t)NT*DM);
  float* xz     = alloc((size_t)NT*2*DI);
  float* xcb    = alloc((size_t)NT*DI);
  float* xdbl   = alloc((size_t)NT*XDC);
  float* dtb    = alloc((size_t)NT*DI);
  float* ylocal = alloc((size_t)NT*DI);
  float* Sbuf   = alloc((size_t)NB*C*DI);
  float* big1   = alloc((size_t)NB*C*NDS*DI);   // Vagg / h_end / gemm partials (dead at gemm time)
  float* big2   = alloc((size_t)NB*C*NDS*DI);   // v_start / h_start / gemm partial overflow
  float* partb  = big1;                          // SK partials: max 16*NT*DM = 12.58M floats = big1+big2

  const float* xcur = x;
  float* nxt = xa;
  for (int l=0; l<2; l++){
    const float* inw_l = in_w   + (size_t)l*2*DI*DM;
    const float* cw_l  = conv_w + (size_t)l*DI*4;
    const float* cb_l  = conv_b + (size_t)l*DI;
    const float* xpw_l = xp_w   + (size_t)l*XDC*DI;
    const float* dtw_l = dtp_w  + (size_t)l*DI*DTR;
    const float* dtbi  = dtp_b  + (size_t)l*DI;
    const float* al_l  = A_log  + (size_t)l*DI*NDS;
    const float* d_l   = Dp     + (size_t)l*DI;
    const float* ow_l  = out_w  + (size_t)l*DM*DI;
    const float* nw_l  = norm_w + (size_t)l*DM;

    rms_k<<<dim3(NT), dim3(256), 0, stream>>>(xcur, nw_l, xn);
    // in_proj: M=NT, N=2*DI, K=DM, SK=4 -> 24*8*4 = 768 blocks (3/CU)
    gemm128<0><<<dim3(2*DI/128, NT/128, skin), dim3(256), 0, stream>>>(
        xn, DM, inw_l, DM, xz, partb, nullptr, NT, 2*DI, DM, skin);
    reduce_k<0><<<dim3((NT*2*DI+255)/256), dim3(256), 0, stream>>>(partb, xz, nullptr, NT*2*DI, skin);
    conv_k<<<dim3(DI/256, NT), dim3(256), 0, stream>>>(xz, cw_l, cb_l, xcb);
    // x_proj: M=NT, N=80, K=DI, SK=8 -> 2*16*8 = 256 blocks
    gemm64<0><<<dim3((XDC+63)/64, NT/64, skx), dim3(256), 0, stream>>>(
        xcb, DI, xpw_l, DI, xdbl, partb, nullptr, NT, XDC, DI, skx);
    reduce_k<0><<<dim3((NT*XDC+255)/256), dim3(256), 0, stream>>>(partb, xdbl, nullptr, NT*XDC, skx);
    // dt_proj: M=NT, N=DI, K=48 -> 64^2 tiles: 24*16 = 384 blocks
    gemm64<1><<<dim3(DI/64, NT/64, 1), dim3(256), 0, stream>>>(
        xdbl, XDC, dtw_l, DTR, dtb, partb, dtbi, NT, DI, DTR, 1);
    vagg_k<<<dim3(DI/256, C, NB), dim3(256), 0, stream>>>(dtb, xcb, xdbl, big1, Sbuf, C, T);
    vcomb_k<<<dim3(DI/256, NDS, NB), dim3(256), 0, stream>>>(big1, big2, C, betaT);
    scan_k<<<dim3(C, NB), dim3(512), 0, stream>>>(big2, dtb, xcb, xdbl, al_l, ylocal, big1, C, T);
    hcomb_k<<<dim3(DI/256, NDS, NB), dim3(256), 0, stream>>>(big1, Sbuf, al_l, big2, C);
    yepi_k<<<dim3(DI/256, NT), dim3(256), 0, stream>>>(ylocal, big2, dtb, xdbl, al_l, d_l, xcb, xz, C, T);
    // out_proj: M=NT, N=DM, K=DI, SK=16 -> 6*8*16 = 768 blocks (3/CU)
    gemm128<2><<<dim3(DM/128, NT/128, skout), dim3(256), 0, stream>>>(
        xz, 2*DI, ow_l, DI, nxt, partb, xcur, NT, DM, DI, skout);
    reduce_k<2><<<dim3((NT*DM+255)/256), dim3(256), 0, stream>>>(partb, nxt, xcur, NT*DM, skout);
    xcur = nxt; nxt = xb;
  }
  rms_k<<<dim3(NT), dim3(256), 0, stream>>>(xcur, fnorm, (float*)d_out);
}

// Round 3
// 591.131 us; speedup vs baseline: 1.6902x; 1.2891x over previous
//
#include <hip/hip_runtime.h>
#include <math.h>

#define DM   768
#define DI   1536
#define NDS  16
#define DTR  48
#define XDC  80
#define NB   2
#define SEQL 512
#define NT   (NB*SEQL)
#define BETA 0.9f
#define NSA  3.4445f
#define NSB  (-4.775f)
#define NSC  2.0315f
#define LOG2E 1.4426950408889634f

typedef __attribute__((ext_vector_type(8))) short short8v;
typedef __attribute__((ext_vector_type(4))) float f32x4;

__device__ __forceinline__ float silu_(float x){ return x / (1.f + __expf(-x)); }
__device__ __forceinline__ unsigned short bfr(float x){
  unsigned u = __float_as_uint(x);
  return (unsigned short)((u + 0x7fffu + ((u>>16)&1u)) >> 16);
}
__device__ __forceinline__ void gl_lds16(const unsigned short* g, unsigned short* l){
  __builtin_amdgcn_global_load_lds((const __attribute__((address_space(1))) void*)g,
                                   (__attribute__((address_space(3))) void*)l, 16, 0, 0);
}

// ---------------- rmsnorm: one block per token; BF=1 -> bf16 output ----------------
template<int BF>
__global__ void rms_k(const float* __restrict__ X, const float* __restrict__ W,
                      void* __restrict__ Ov)
{
  const int g = blockIdx.x, tid = threadIdx.x;
  const float* xr = X + (size_t)g*DM;
  float x0 = xr[tid], x1 = xr[tid+256], x2 = xr[tid+512];
  float ss = x0*x0 + x1*x1 + x2*x2;
  #pragma unroll
  for (int m=1; m<=32; m<<=1) ss += __shfl_xor(ss, m);
  __shared__ float ws[4];
  if ((tid & 63) == 0) ws[tid>>6] = ss;
  __syncthreads();
  float sc = rsqrtf((ws[0]+ws[1]+ws[2]+ws[3])*(1.f/DM) + 1e-5f);
  if (BF){
    unsigned short* o = (unsigned short*)Ov + (size_t)g*DM;
    o[tid]     = bfr(x0*sc*W[tid]);
    o[tid+256] = bfr(x1*sc*W[tid+256]);
    o[tid+512] = bfr(x2*sc*W[tid+512]);
  } else {
    float* o = (float*)Ov + (size_t)g*DM;
    o[tid]     = x0*sc*W[tid];
    o[tid+256] = x1*sc*W[tid+256];
    o[tid+512] = x2*sc*W[tid+512];
  }
}

// ---------------- f32 -> bf16 cast (vectorized) ----------------
__global__ void castbf_k(const float* __restrict__ in, unsigned short* __restrict__ out, int n4)
{
  const int i = blockIdx.x*256 + threadIdx.x;
  if (i >= n4) return;
  float4 v = ((const float4*)in)[i];
  ushort4 o;
  o.x = bfr(v.x); o.y = bfr(v.y); o.z = bfr(v.z); o.w = bfr(v.w);
  ((ushort4*)out)[i] = o;
}

// ---------------- bf16 MFMA GEMM (m97 structure): C = A * B^T ----------------
// A [M][lda] bf16 k-contig, B [N][ldb] bf16 k-contig. Out f32 [M][N].
// EPI: 0 none, 2 add aux[row*N+col] (only when SK==1). SK>1 -> Part.
template<int EPI>
__global__ __launch_bounds__(256) void gemm_mf(
    const unsigned short* __restrict__ Abf, int lda,
    const unsigned short* __restrict__ Bbf, int ldb,
    float* __restrict__ Out, float* __restrict__ Part,
    const float* __restrict__ aux,
    int M, int N, int K, int SK)
{
  __shared__ unsigned short As[128*32];
  __shared__ unsigned short Bs[128*32];
  const int tid  = threadIdx.x;
  const int wid  = tid >> 6, lane = tid & 63;
  const int bm   = blockIdx.y*128, bn = blockIdx.x*128;
  const int kc   = K/SK, kBeg = blockIdx.z*kc, kEnd = kBeg + kc;
  const int wr   = (wid>>1)*64, wc = (wid&1)*64;

  f32x4 acc[4][4];
  #pragma unroll
  for (int m=0;m<4;m++)
    #pragma unroll
    for (int n=0;n<4;n++) acc[m][n] = (f32x4){0.f,0.f,0.f,0.f};

  // staging: 2 chunks of 1KB per wave per tile (A and B each 8KB)
  const int e0 = (wid*2)*512 + lane*8;      // elem offset chunk r=0
  const int e1 = e0 + 512;                  // chunk r=1
  const int r0 = e0 >> 5, k0e = e0 & 31;
  const int r1 = e1 >> 5, k1e = e1 & 31;
  const unsigned short* Ag0 = Abf + (size_t)(bm + r0)*lda + k0e;
  const unsigned short* Ag1 = Abf + (size_t)(bm + r1)*lda + k1e;
  const unsigned short* Bg0 = Bbf + (size_t)(bn + r0)*ldb + k0e;
  const unsigned short* Bg1 = Bbf + (size_t)(bn + r1)*ldb + k1e;

  // fragment read offsets (elems)
  int aoff[4], boff[4];
  #pragma unroll
  for (int m=0;m<4;m++) aoff[m] = (wr + m*16 + (lane&15))*32 + (lane>>4)*8;
  #pragma unroll
  for (int n=0;n<4;n++) boff[n] = (wc + n*16 + (lane&15))*32 + (lane>>4)*8;

  for (int k0 = kBeg; k0 < kEnd; k0 += 32){
    gl_lds16(Ag0 + k0, As + e0);
    gl_lds16(Ag1 + k0, As + e1);
    gl_lds16(Bg0 + k0, Bs + e0);
    gl_lds16(Bg1 + k0, Bs + e1);
    __syncthreads();
    short8v af[4], bfv[4];
    #pragma unroll
    for (int m=0;m<4;m++) af[m]  = *(const short8v*)(As + aoff[m]);
    #pragma unroll
    for (int n=0;n<4;n++) bfv[n] = *(const short8v*)(Bs + boff[n]);
    #pragma unroll
    for (int m=0;m<4;m++)
      #pragma unroll
      for (int n=0;n<4;n++)
        acc[m][n] = __builtin_amdgcn_mfma_f32_16x16x32_bf16(af[m], bfv[n], acc[m][n], 0, 0, 0);
    __syncthreads();
  }

  #pragma unroll
  for (int m=0;m<4;m++){
    const int rowb = bm + wr + m*16 + (lane>>4)*4;
    #pragma unroll
    for (int n=0;n<4;n++){
      const int col = bn + wc + n*16 + (lane&15);
      #pragma unroll
      for (int r=0;r<4;r++){
        const int row = rowb + r;
        float vv = acc[m][n][r];
        if (SK == 1){
          if (EPI==2) vv += aux[(size_t)row*N + col];
          Out[(size_t)row*N + col] = vv;
        } else {
          Part[(size_t)blockIdx.z*M*N + (size_t)row*N + col] = vv;
        }
      }
    }
  }
}

// ---------------- f32 GEMM (small shapes): C[r,c]=sum_k A[r*lda+k]*B[c*ldb+k] ----------------
template<int EPI>
__global__ void gemm64(const float* __restrict__ A, int lda,
                       const float* __restrict__ Bw, int ldb,
                       float* __restrict__ Out, float* __restrict__ Part,
                       const float* __restrict__ aux,
                       int M, int N, int K, int SK)
{
  __shared__ float As[16][64], Bs[16][64];
  const int tid = threadIdx.x;
  const int bm = blockIdx.y*64, bn = blockIdx.x*64;
  const int kc = K/SK, kBeg = blockIdx.z*kc, kEnd = kBeg + kc;
  const int lr = tid>>2, lk = (tid&3)<<2;
  const int tx = tid&15, ty = tid>>4;
  float acc[4][4];
  #pragma unroll
  for (int i=0;i<4;i++)
    #pragma unroll
    for (int j=0;j<4;j++) acc[i][j] = 0.f;
  const float* Ap = A + (size_t)(bm+lr)*lda + lk;
  const bool bok = (bn+lr) < N;
  const float* Bp = Bw + (size_t)(bn+lr)*ldb + lk;
  for (int k0=kBeg; k0<kEnd; k0+=16){
    float4 a0 = *(const float4*)(Ap + k0);
    float4 b0 = {0,0,0,0};
    if (bok) b0 = *(const float4*)(Bp + k0);
    __syncthreads();
    As[lk+0][lr]=a0.x; As[lk+1][lr]=a0.y; As[lk+2][lr]=a0.z; As[lk+3][lr]=a0.w;
    Bs[lk+0][lr]=b0.x; Bs[lk+1][lr]=b0.y; Bs[lk+2][lr]=b0.z; Bs[lk+3][lr]=b0.w;
    __syncthreads();
    #pragma unroll
    for (int kk=0;kk<16;kk++){
      float a[4], b[4];
      *(float4*)a = *(const float4*)&As[kk][ty*4];
      *(float4*)b = *(const float4*)&Bs[kk][tx*4];
      #pragma unroll
      for (int i=0;i<4;i++)
        #pragma unroll
        for (int j=0;j<4;j++) acc[i][j] = fmaf(a[i], b[j], acc[i][j]);
    }
  }
  #pragma unroll
  for (int i=0;i<4;i++){
    const int row = bm + ty*4 + i;
    #pragma unroll
    for (int j=0;j<4;j++){
      const int col = bn + tx*4 + j;
      if (col < N){
        if (SK == 1){
          float vv = acc[i][j];
          if (EPI==1){ vv += aux[col]; vv = fmaxf(vv,0.f) + log1pf(__expf(-fabsf(vv))); }
          if (EPI==2){ vv += aux[(size_t)row*N+col]; }
          Out[(size_t)row*N+col] = vv;
        } else {
          Part[(size_t)blockIdx.z*M*N + (size_t)row*N+col] = acc[i][j];
        }
      }
    }
  }
}

template<int EPI>
__global__ void reduce_k(const float* __restrict__ Part, float* __restrict__ Out,
                         const float* __restrict__ aux, int MN, int SK)
{
  const int i = blockIdx.x*256 + threadIdx.x;
  if (i >= MN) return;
  float s = 0.f;
  for (int z=0; z<SK; z++) s += Part[(size_t)z*MN + i];
  if (EPI==2) s += aux[i];
  Out[i] = s;
}

// ---------------- causal depthwise conv (width 4) + bias + silu ----------------
__global__ void conv_k(const float* __restrict__ xz, const float* __restrict__ cw,
                       const float* __restrict__ cb, float* __restrict__ xc)
{
  const int d = blockIdx.x*256 + threadIdx.x;
  const int g = blockIdx.y;
  const int b = g >> 9, t = g & (SEQL-1);
  float4 w4 = *(const float4*)(cw + (size_t)d*4);
  const float wk[4] = {w4.x, w4.y, w4.z, w4.w};
  const float* col = xz + ((size_t)b*SEQL)*(2*DI) + d;
  float acc = cb[d];
  #pragma unroll
  for (int k=0;k<4;k++){
    int tt = t - 3 + k;
    if (tt >= 0) acc = fmaf(wk[k], col[(size_t)tt*(2*DI)], acc);
  }
  xc[(size_t)g*DI + d] = silu_(acc);
}

// ---------------- pass 1: per-chunk v aggregates + chunk dt sums ----------------
__global__ void vagg_k(const float* __restrict__ dt, const float* __restrict__ xcp,
                       const float* __restrict__ xdbl, float* __restrict__ Vagg,
                       float* __restrict__ S, int C, int T)
{
  const int d = blockIdx.x*256 + threadIdx.x;
  const int c = blockIdx.y, b = blockIdx.z;
  float acc[16];
  #pragma unroll
  for (int n=0;n<16;n++) acc[n] = 0.f;
  float sdt = 0.f;
  for (int s=0;s<T;s++){
    const int g = b*SEQL + c*T + s;
    float dv = dt[(size_t)g*DI + d];
    float w  = dv * xcp[(size_t)g*DI + d];
    sdt += dv;
    #pragma unroll
    for (int n=0;n<16;n++) acc[n] = fmaf(BETA, acc[n], w * xdbl[(size_t)g*XDC + 48 + n]);
  }
  const size_t base = ((size_t)(b*C + c)*NDS)*DI + d;
  #pragma unroll
  for (int n=0;n<16;n++) Vagg[base + (size_t)n*DI] = acc[n];
  S[(size_t)(b*C + c)*DI + d] = sdt;
}

// ---------------- pass 2: sequential-over-chunks combine for v_start ----------------
__global__ void vcomb_k(const float* __restrict__ Vagg, float* __restrict__ vst,
                        int C, float betaT)
{
  const int d = blockIdx.x*256 + threadIdx.x;
  const int n = blockIdx.y, b = blockIdx.z;
  const size_t stride = (size_t)NDS*DI;
  size_t idx = ((size_t)(b*C)*NDS + n)*DI + d;
  float v = 0.f;
  for (int c=0;c<C;c++){
    vst[idx] = v;
    v = fmaf(betaT, v, Vagg[idx]);
    idx += stride;
  }
}

// ---------------- pass 3: in-chunk scan with Newton-Schulz ----------------
__global__ __launch_bounds__(512,2) void scan_k(
    const float* __restrict__ vst, const float* __restrict__ dt,
    const float* __restrict__ xcp, const float* __restrict__ xdbl,
    const float* __restrict__ A_log,
    float* __restrict__ ylocal, float* __restrict__ hend,
    int C, int T)
{
  const int c = blockIdx.x, b = blockIdx.y;
  const int tid = threadIdx.x;
  const int lane = tid & 63;
  const int wid = tid >> 6;
  __shared__ float Rmat[16][17];
  __shared__ float Qmat[16][17];
  __shared__ float red[8][20];
  __shared__ float sBC[2][32];
  __shared__ float gram[32][136];

  int pi = 0, pj = 0;
  if (tid < 136){
    int pp = tid;
    while (pp >= 16 - pi){ pp -= 16 - pi; pi++; }
    pj = pi + pp;
  }

  float v[3][16];
  {
    const float* vs = vst + ((size_t)(b*C + c)*NDS)*DI;
    #pragma unroll
    for (int j=0;j<3;j++)
      #pragma unroll
      for (int n=0;n<16;n++) v[j][n] = vs[(size_t)n*DI + tid + j*512];
  }

  {
    int p = 0;
    #pragma unroll
    for (int i2=0;i2<16;i2++){
      #pragma unroll
      for (int j2=i2;j2<16;j2++){
        float sR = v[0][i2]*v[0][j2];
        sR = fmaf(v[1][i2], v[1][j2], sR);
        sR = fmaf(v[2][i2], v[2][j2], sR);
        sR += __shfl_xor(sR, 1);
        sR += __shfl_xor(sR, 2);
        sR += __shfl_xor(sR, 4);
        sR += __shfl_xor(sR, 8);
        if ((lane & 15) == (p & 15)) gram[(wid<<2) | (lane>>4)][p] = sR;
        p++;
      }
    }
  }
  __syncthreads();
  if (tid < 136){
    float r = 0.f;
    #pragma unroll
    for (int q=0;q<32;q++) r += gram[q][tid];
    Rmat[pi][pj] = r; Rmat[pj][pi] = r;
  }

  float h[3][16], Ar[3][16];
  #pragma unroll
  for (int j=0;j<3;j++){
    const float* arow = A_log + (size_t)(tid + j*512)*NDS;
    #pragma unroll
    for (int n=0;n<16;n++){
      Ar[j][n] = -__expf(arow[n]) * LOG2E;
      h[j][n] = 0.f;
    }
  }

  const int t0 = c*T;
  for (int s=0; s<T; s++){
    const int g = b*SEQL + t0 + s;
    const int par = s & 1;
    if (tid < 32) sBC[par][tid] = xdbl[(size_t)g*XDC + 48 + tid];
    float dtv[3], w3[3];
    #pragma unroll
    for (int j=0;j<3;j++){
      dtv[j] = dt[(size_t)g*DI + tid + j*512];
      w3[j]  = dtv[j] * xcp[(size_t)g*DI + tid + j*512];
    }
    float ps[17];
    #pragma unroll
    for (int n=0;n<16;n++){
      float t1 = v[0][n]*w3[0];
      t1 = fmaf(v[1][n], w3[1], t1);
      ps[n] = fmaf(v[2][n], w3[2], t1);
    }
    ps[16] = w3[0]*w3[0] + w3[1]*w3[1] + w3[2]*w3[2];
    #pragma unroll
    for (int m=1; m<=32; m<<=1){
      #pragma unroll
      for (int k=0;k<17;k++) ps[k] += __shfl_xor(ps[k], m);
    }
    if (lane == 0){
      #pragma unroll
      for (int k=0;k<17;k++) red[wid][k] = ps[k];
    }
    __syncthreads();
    #pragma unroll
    for (int j=0;j<3;j++)
      #pragma unroll
      for (int n=0;n<16;n++) v[j][n] = fmaf(BETA, v[j][n], w3[j]*sBC[par][n]);
    if (tid < 136){
      float p_i=0.f, p_j=0.f, sw=0.f;
      #pragma unroll
      for (int q=0;q<8;q++){ p_i += red[q][pi]; p_j += red[q][pj]; sw += red[q][16]; }
      const float bi = sBC[par][pi], bj = sBC[par][pj];
      float rn = BETA*BETA*Rmat[pi][pj];
      rn = fmaf(BETA, p_i*bj + bi*p_j, rn);
      rn = fmaf(sw, bi*bj, rn);
      Rmat[pi][pj] = rn; if (pi != pj) Rmat[pj][pi] = rn;
    }
    __syncthreads();
    float tr = 0.f;
    #pragma unroll
    for (int i2=0;i2<16;i2++) tr += Rmat[i2][i2];
    const float nu = sqrtf(tr) + 1e-7f;
    const float inv_nu = 1.f/nu;
    const float inv2 = inv_nu*inv_nu;
    const float inv4 = inv2*inv2;
    if (tid < 136){
      float a2 = 0.f;
      #pragma unroll
      for (int k=0;k<16;k++) a2 = fmaf(Rmat[pi][k], Rmat[k][pj], a2);
      float q = NSB*inv2*Rmat[pi][pj] + NSC*inv4*a2;
      if (pi == pj) q += NSA;
      Qmat[pi][pj] = q; if (pi != pj) Qmat[pj][pi] = q;
    }
    __syncthreads();
    float yv[3] = {0.f, 0.f, 0.f};
    #pragma unroll
    for (int n=0;n<16;n++){
      float a0=0.f, a1=0.f, a2v=0.f;
      #pragma unroll
      for (int k=0;k<16;k++){
        const float q = Qmat[k][n];
        a0  = fmaf(v[0][k], q, a0);
        a1  = fmaf(v[1][k], q, a1);
        a2v = fmaf(v[2][k], q, a2v);
      }
      const float Cn = sBC[par][16+n];
      float acc3[3] = {a0, a1, a2v};
      #pragma unroll
      for (int j=0;j<3;j++){
        const float e = exp2f(dtv[j]*Ar[j][n]);
        h[j][n] = fmaf(e, h[j][n], acc3[j]*inv_nu);
        yv[j] = fmaf(h[j][n], Cn, yv[j]);
      }
    }
    ylocal[(size_t)g*DI + tid]        = yv[0];
    ylocal[(size_t)g*DI + tid + 512]  = yv[1];
    ylocal[(size_t)g*DI + tid + 1024] = yv[2];
  }
  float* he = hend + ((size_t)(b*C + c)*NDS)*DI;
  #pragma unroll
  for (int j=0;j<3;j++)
    #pragma unroll
    for (int n=0;n<16;n++) he[(size_t)n*DI + tid + j*512] = h[j][n];
}

// ---------------- pass 4: combine h chunk-starts ----------------
__global__ void hcomb_k(const float* __restrict__ hend, const float* __restrict__ S,
                        const float* __restrict__ A_log, float* __restrict__ hst, int C)
{
  const int d = blockIdx.x*256 + threadIdx.x;
  const int n = blockIdx.y, b = blockIdx.z;
  const float An = -__expf(A_log[(size_t)d*NDS + n]);
  const size_t stride = (size_t)NDS*DI;
  size_t idx  = ((size_t)(b*C)*NDS + n)*DI + d;
  size_t sidx = (size_t)(b*C)*DI + d;
  float hv = 0.f;
  for (int c=0;c<C;c++){
    hst[idx] = hv;
    hv = fmaf(__expf(An * S[sidx]), hv, hend[idx]);
    idx += stride; sidx += DI;
  }
}

// ---------------- pass 5: y epilogue -> bf16 gated output ----------------
__global__ void yepi_k(const float* __restrict__ ylocal, const float* __restrict__ hst,
                       const float* __restrict__ dt, const float* __restrict__ xdbl,
                       const float* __restrict__ A_log, const float* __restrict__ Dv,
                       const float* __restrict__ xcp, const float* __restrict__ xz,
                       unsigned short* __restrict__ ybf,
                       int C, int T)
{
  const int d = blockIdx.x*256 + threadIdx.x;
  const int g = blockIdx.y;
  const int b = g >> 9, t = g & (SEQL-1);
  const int c = t / T, s0 = c*T;
  float ddt = 0.f;
  for (int r=s0; r<=t; r++) ddt += dt[(size_t)(b*SEQL + r)*DI + d];
  const float* hs = hst + ((size_t)(b*C + c)*NDS)*DI + d;
  const float* ar = A_log + (size_t)d*NDS;
  float corr = 0.f;
  #pragma unroll
  for (int n=0;n<16;n++){
    float An = -__expf(ar[n]);
    float Cn = xdbl[(size_t)g*XDC + 64 + n];
    corr = fmaf(hs[(size_t)n*DI] * __expf(An*ddt), Cn, corr);
  }
  float y = ylocal[(size_t)g*DI + d] + corr + Dv[d]*xcp[(size_t)g*DI + d];
  float z = xz[(size_t)g*(2*DI) + DI + d];
  ybf[(size_t)g*DI + d] = bfr(y * silu_(z));
}

// ============================== host ==============================
extern "C" void kernel_launch(void* const* d_in, const int* in_sizes, int n_in,
                              void* d_out, int out_size, void* d_ws, size_t ws_size,
                              hipStream_t stream)
{
  (void)in_sizes; (void)n_in; (void)out_size; (void)ws_size;
  const float* x      = (const float*)d_in[0];
  const float* in_w   = (const float*)d_in[1];
  const float* conv_w = (const float*)d_in[2];
  const float* conv_b = (const float*)d_in[3];
  const float* xp_w   = (const float*)d_in[4];
  const float* dtp_w  = (const float*)d_in[5];
  const float* dtp_b  = (const float*)d_in[6];
  const float* A_log  = (const float*)d_in[7];
  const float* Dp     = (const float*)d_in[8];
  const float* out_w  = (const float*)d_in[9];
  const float* norm_w = (const float*)d_in[10];
  const float* fnorm  = (const float*)d_in[11];

  const int C = 128, T = SEQL / C;
  const float betaT = powf(BETA, (float)T);
  const int skx = 8, skout = 8;

  float* w0 = (float*)d_ws; size_t off = 0;
  auto alloc = [&](size_t n)->float*{ float* p = w0 + off; off += (n + 63) & ~(size_t)63; return p; };
  float* xa     = alloc((size_t)NT*DM);
  float* xb     = alloc((size_t)NT*DM);
  float* bfA    = alloc((size_t)NT*DI/2);       // bf16 A-matrices: xnb (rms out) then ybf (gated y)
  float* xz     = alloc((size_t)NT*2*DI);
  float* xcb    = alloc((size_t)NT*DI);
  float* xdbl   = alloc((size_t)NT*XDC);
  float* dtb    = alloc((size_t)NT*DI);
  float* ylocal = alloc((size_t)NT*DI);
  float* Sbuf   = alloc((size_t)NB*C*DI);
  float* big1   = alloc((size_t)NB*C*NDS*DI);   // Vagg / h_end / gemm partials
  float* big2   = alloc((size_t)NB*C*NDS*DI);   // wbf / v_start / h_start

  unsigned short* xnb = (unsigned short*)bfA;   // [NT][DM]
  unsigned short* ybf = (unsigned short*)bfA;   // [NT][DI] (sequential lifetime with xnb)
  unsigned short* wbf = (unsigned short*)big2;  // bf16 weights (lifetime ends before vcomb writes big2)
  float* partb = big1;

  const float* xcur = x;
  float* nxt = xa;
  for (int l=0; l<2; l++){
    const float* inw_l = in_w   + (size_t)l*2*DI*DM;
    const float* cw_l  = conv_w + (size_t)l*DI*4;
    const float* cb_l  = conv_b + (size_t)l*DI;
    const float* xpw_l = xp_w   + (size_t)l*XDC*DI;
    const float* dtw_l = dtp_w  + (size_t)l*DI*DTR;
    const float* dtbi  = dtp_b  + (size_t)l*DI;
    const float* al_l  = A_log  + (size_t)l*DI*NDS;
    const float* d_l   = Dp     + (size_t)l*DI;
    const float* ow_l  = out_w  + (size_t)l*DM*DI;
    const float* nw_l  = norm_w + (size_t)l*DM;

    // cast in_proj weight to bf16 (wbf) ; rmsnorm -> bf16 A
    castbf_k<<<dim3((2*DI*DM/4+255)/256), dim3(256), 0, stream>>>(inw_l, wbf, 2*DI*DM/4);
    rms_k<1><<<dim3(NT), dim3(256), 0, stream>>>(xcur, nw_l, xnb);
    // in_proj MFMA: M=NT, N=2*DI, K=DM, no split-K, direct write
    gemm_mf<0><<<dim3(2*DI/128, NT/128, 1), dim3(256), 0, stream>>>(
        xnb, DM, wbf, DM, xz, nullptr, nullptr, NT, 2*DI, DM, 1);
    conv_k<<<dim3(DI/256, NT), dim3(256), 0, stream>>>(xz, cw_l, cb_l, xcb);
    // x_proj (f32): M=NT, N=80, K=DI, SK=8
    gemm64<0><<<dim3((XDC+63)/64, NT/64, skx), dim3(256), 0, stream>>>(
        xcb, DI, xpw_l, DI, xdbl, partb, nullptr, NT, XDC, DI, skx);
    reduce_k<0><<<dim3((NT*XDC+255)/256), dim3(256), 0, stream>>>(partb, xdbl, nullptr, NT*XDC, skx);
    // dt_proj (f32): M=NT, N=DI, K=48
    gemm64<1><<<dim3(DI/64, NT/64, 1), dim3(256), 0, stream>>>(
        xdbl, XDC, dtw_l, DTR, dtb, partb, dtbi, NT, DI, DTR, 1);
    vagg_k<<<dim3(DI/256, C, NB), dim3(256), 0, stream>>>(dtb, xcb, xdbl, big1, Sbuf, C, T);
    vcomb_k<<<dim3(DI/256, NDS, NB), dim3(256), 0, stream>>>(big1, big2, C, betaT);
    scan_k<<<dim3(C, NB), dim3(512), 0, stream>>>(big2, dtb, xcb, xdbl, al_l, ylocal, big1, C, T);
    hcomb_k<<<dim3(DI/256, NDS, NB), dim3(256), 0, stream>>>(big1, Sbuf, al_l, big2, C);
    yepi_k<<<dim3(DI/256, NT), dim3(256), 0, stream>>>(ylocal, big2, dtb, xdbl, al_l, d_l, xcb, xz, ybf, C, T);
    // cast out_proj weight (big2 dead now) ; out_proj MFMA SK=8 -> partials big1 ; fused residual reduce
    castbf_k<<<dim3((DM*DI/4+255)/256), dim3(256), 0, stream>>>(ow_l, wbf, DM*DI/4);
    gemm_mf<0><<<dim3(DM/128, NT/128, skout), dim3(256), 0, stream>>>(
        ybf, DI, wbf, DI, nxt, partb, nullptr, NT, DM, DI, skout);
    reduce_k<2><<<dim3((NT*DM+255)/256), dim3(256), 0, stream>>>(partb, nxt, xcur, NT*DM, skout);
    xcur = nxt; nxt = xb;
  }
  rms_k<0><<<dim3(NT), dim3(256), 0, stream>>>(xcur, fnorm, (float*)d_out);
}